// Round 14
// baseline (1221.347 us; speedup 1.0000x reference)
//
#include <hip/hip_runtime.h>

// GRU: B=128, T=2048, H=128.
// K1 gru_proj: xz/xr/xh = x @ W^T + b via bf16 MFMA. Gate inputs PRESCALED:
//   xz,xr by -log2(e) (sigmoid as rcp(1+exp2(x))), xh by +2*log2(e)
//   (tanh as fma(-2, rcp(exp2(y)+1), 1)). U-frags likewise scaled at load.
// K2 gru_rec8d: R13 structure (1 batch/block x 128 blocks, 8 waves x 16
//   units, broadcast-A MFMA, 4 independent MFMAs/gate + add tree, 2
//   lgkm-only barriers/step, 6-deep prefetch, refill-after-write,
//   fire-and-forget stores) with ONE ds_read_b128 per phase per lane:
//   lane l reads slice (l&3) of h/rh; the 4 MFMA A-fragments are rebuilt
//   via update_dpp quad_perm broadcasts (LDS-pipe instr count 4x down,
//   work moved to the ~90%-idle VALU).

#define T_LEN 2048
#define H_DIM 128

typedef __attribute__((ext_vector_type(8))) __bf16 bf16x8;
typedef __attribute__((ext_vector_type(4))) float f32x4;
typedef __attribute__((ext_vector_type(4))) unsigned int u32x4;

// raw barrier: drains LDS ops (cross-wave visibility) but NOT vmcnt. [m201]
#define BARRIER() asm volatile("s_waitcnt lgkmcnt(0)\n\ts_barrier" ::: "memory")

#define KNEG -1.4426950408889634f   // -log2(e): z,r prescale
#define KPOS  2.8853900817779268f   // 2*log2(e): h prescale

__device__ __forceinline__ unsigned short f2bf_bits(float f){
  __bf16 b = (__bf16)f;                     // fptrunc, RNE
  return __builtin_bit_cast(unsigned short, b);
}
__device__ __forceinline__ float bf2f(unsigned short s){
  unsigned int u = ((unsigned int)s) << 16;
  return __builtin_bit_cast(float, u);
}
// prescaled sigmoid: input already -log2e * logit
__device__ __forceinline__ float sigm_pre(float x){
  return __builtin_amdgcn_rcpf(1.0f + __builtin_amdgcn_exp2f(x));
}
// prescaled tanh: input already 2*log2e * arg
__device__ __forceinline__ float tanh_pre(float y){
  float t = __builtin_amdgcn_rcpf(__builtin_amdgcn_exp2f(y) + 1.0f);
  return fmaf(-2.0f, t, 1.0f);              // inf-safe: ->1 / ->-1
}
// broadcast quad-lane CTRL-pattern's 16B value to all 4 lanes of each quad
template<int CTRL>
__device__ __forceinline__ bf16x8 quad_bcast(bf16x8 v){
  u32x4 u = __builtin_bit_cast(u32x4, v);
  u32x4 r;
  r[0] = (unsigned)__builtin_amdgcn_update_dpp(0, (int)u[0], CTRL, 0xF, 0xF, true);
  r[1] = (unsigned)__builtin_amdgcn_update_dpp(0, (int)u[1], CTRL, 0xF, 0xF, true);
  r[2] = (unsigned)__builtin_amdgcn_update_dpp(0, (int)u[2], CTRL, 0xF, 0xF, true);
  r[3] = (unsigned)__builtin_amdgcn_update_dpp(0, (int)u[3], CTRL, 0xF, 0xF, true);
  return __builtin_bit_cast(bf16x8, r);
}

// ---------------- projection GEMM (R1-verified + prescale epilogue) --------

__device__ __forceinline__ void stage_mat128(const float* __restrict__ src,
                                             __bf16 (*dst)[136], int tid){
  #pragma unroll
  for (int rep = 0; rep < 8; ++rep){
    int fi = rep * 2048 + tid * 4;
    float4 v = *reinterpret_cast<const float4*>(src + fi);
    int m = fi >> 7;
    int k = fi & 127;
    unsigned long long pk =
        (unsigned long long)f2bf_bits(v.x)
      | ((unsigned long long)f2bf_bits(v.y) << 16)
      | ((unsigned long long)f2bf_bits(v.z) << 32)
      | ((unsigned long long)f2bf_bits(v.w) << 48);
    *reinterpret_cast<unsigned long long*>(&dst[m][k]) = pk;
  }
}

__global__ __launch_bounds__(512, 2) void gru_proj(
    const float* __restrict__ x,
    const float* __restrict__ Wz, const float* __restrict__ Wr, const float* __restrict__ Wh,
    const float* __restrict__ bz, const float* __restrict__ br, const float* __restrict__ bh,
    unsigned int* __restrict__ out_zr, unsigned short* __restrict__ out_h)
{
  __shared__ __bf16 xs[128][136];
  __shared__ __bf16 wsh[3][128][136];

  const int tid = threadIdx.x;
  const long Mbase = (long)blockIdx.x * 128;

  stage_mat128(x + Mbase * H_DIM, xs, tid);
  stage_mat128(Wz, wsh[0], tid);
  stage_mat128(Wr, wsh[1], tid);
  stage_mat128(Wh, wsh[2], tid);
  __syncthreads();

  const int w  = tid >> 6, l = tid & 63;
  const int ml = l & 15;
  const int kl = (l >> 4) * 8;
  const int n  = w * 16 + ml;

  bf16x8 bfr[3][4];
  #pragma unroll
  for (int g = 0; g < 3; ++g)
    #pragma unroll
    for (int kk = 0; kk < 4; ++kk)
      bfr[g][kk] = *reinterpret_cast<const bf16x8*>(&wsh[g][n][kk * 32 + kl]);

  const float bzv = bz[n], brv = br[n], bhv = bh[n];

  f32x4 acc[8][3];
  #pragma unroll
  for (int mt = 0; mt < 8; ++mt)
    #pragma unroll
    for (int g = 0; g < 3; ++g)
      acc[mt][g] = (f32x4){0.f, 0.f, 0.f, 0.f};

  #pragma unroll
  for (int mt = 0; mt < 8; ++mt){
    #pragma unroll
    for (int kk = 0; kk < 4; ++kk){
      bf16x8 a = *reinterpret_cast<const bf16x8*>(&xs[mt * 16 + ml][kk * 32 + kl]);
      acc[mt][0] = __builtin_amdgcn_mfma_f32_16x16x32_bf16(a, bfr[0][kk], acc[mt][0], 0, 0, 0);
      acc[mt][1] = __builtin_amdgcn_mfma_f32_16x16x32_bf16(a, bfr[1][kk], acc[mt][1], 0, 0, 0);
      acc[mt][2] = __builtin_amdgcn_mfma_f32_16x16x32_bf16(a, bfr[2][kk], acc[mt][2], 0, 0, 0);
    }
  }

  #pragma unroll
  for (int mt = 0; mt < 8; ++mt){
    #pragma unroll
    for (int p = 0; p < 4; ++p){
      long row = Mbase + mt * 16 + (l >> 4) * 4 + p;
      float vz = (acc[mt][0][p] + bzv) * KNEG;   // prescaled for sigm_pre
      float vr = (acc[mt][1][p] + brv) * KNEG;
      float vh = (acc[mt][2][p] + bhv) * KPOS;   // prescaled for tanh_pre
      unsigned int word = (unsigned int)f2bf_bits(vz)
                        | (((unsigned int)f2bf_bits(vr)) << 16);
      out_zr[row * H_DIM + n] = word;
      out_h [row * H_DIM + n] = f2bf_bits(vh);
    }
  }
}

// ---- recurrence: broadcast-A MFMA, 8 waves, dpp-rebuilt fragments ----------

__device__ __forceinline__ bf16x8 ld_u_frag_s(const float* p, float s){
  float4 a = *reinterpret_cast<const float4*>(p);
  float4 b = *reinterpret_cast<const float4*>(p + 4);
  bf16x8 r;
  r[0]=(__bf16)(a.x*s); r[1]=(__bf16)(a.y*s); r[2]=(__bf16)(a.z*s); r[3]=(__bf16)(a.w*s);
  r[4]=(__bf16)(b.x*s); r[5]=(__bf16)(b.y*s); r[6]=(__bf16)(b.z*s); r[7]=(__bf16)(b.w*s);
  return r;
}

#define MFMA(A, B, C) __builtin_amdgcn_mfma_f32_16x16x32_bf16(A, B, C, 0, 0, 0)

__device__ __forceinline__ void gru_step8(
    int t, int ub, int g8, int l, int w,
    const bf16x8* ufz, const bf16x8* ufr, const bf16x8* ufh,
    __bf16* hx, __bf16* rhx,
    const unsigned int* xzr, const unsigned short* xh, float* out,
    unsigned int& zrw, unsigned short& xhw, float& h_own)
{
  const f32x4 zero = (f32x4){0.f, 0.f, 0.f, 0.f};
  const int tp = (t + 6 < T_LEN) ? t + 6 : T_LEN - 1;   // 6-deep refill slot
  const int u  = w * 16 + (l & 15);
  const int q4 = l & 3;                                 // owned k-window
  const bool own = (l < 16);

  // ---- phase A: ONE ds_read + quad_perm rebuild; r gate; rh write ----
  bf16x8 hv = *reinterpret_cast<const bf16x8*>(&hx[q4 * 32 + g8 * 8]);
  bf16x8 a0 = quad_bcast<0x00>(hv);
  bf16x8 a1 = quad_bcast<0x55>(hv);
  bf16x8 a2 = quad_bcast<0xAA>(hv);
  bf16x8 a3 = quad_bcast<0xFF>(hv);
  f32x4 r0 = MFMA(a0, ufr[0], zero);
  f32x4 r1 = MFMA(a1, ufr[1], zero);
  f32x4 r2 = MFMA(a2, ufr[2], zero);
  f32x4 r3 = MFMA(a3, ufr[3], zero);

  // consume this step's prefetched inputs (pre-refill)
  float xzv = bf2f((unsigned short)(zrw & 0xffffu));
  float xrv = bf2f((unsigned short)(zrw >> 16));
  float xhv = bf2f(xhw);

  float rg = sigm_pre(xrv + ((r0[0] + r1[0]) + (r2[0] + r3[0])));
  float rh = rg * h_own;
  if (own)
    rhx[u] = (__bf16)rh;                 // b16, 2 lanes/dword: conflict-free
  zrw = xzr[ub + tp * H_DIM];            // refill AFTER write: covers latency
  BARRIER();                             // rh visible

  // ---- phase B: z (register frags; hides under rh read) + h~ + update ----
  bf16x8 rv = *reinterpret_cast<const bf16x8*>(&rhx[q4 * 32 + g8 * 8]);
  f32x4 z0 = MFMA(a0, ufz[0], zero);     // issue before rv arrives
  f32x4 z1 = MFMA(a1, ufz[1], zero);
  f32x4 z2 = MFMA(a2, ufz[2], zero);
  f32x4 z3 = MFMA(a3, ufz[3], zero);
  bf16x8 b0 = quad_bcast<0x00>(rv);
  bf16x8 b1 = quad_bcast<0x55>(rv);
  bf16x8 b2 = quad_bcast<0xAA>(rv);
  bf16x8 b3 = quad_bcast<0xFF>(rv);
  f32x4 h0 = MFMA(b0, ufh[0], zero);
  f32x4 h1 = MFMA(b1, ufh[1], zero);
  f32x4 h2 = MFMA(b2, ufh[2], zero);
  f32x4 h3 = MFMA(b3, ufh[3], zero);

  float zg = sigm_pre(xzv + ((z0[0] + z1[0]) + (z2[0] + z3[0])));
  float hc = tanh_pre(xhv + ((h0[0] + h1[0]) + (h2[0] + h3[0])));
  float hn = fmaf(zg, hc - h_own, h_own);               // (1-z)h + z*hc
  h_own = hn;
  if (own){
    hx[u] = (__bf16)hn;
    out[ub + t * H_DIM] = hn;                           // fire-and-forget
  }
  xhw = xh[ub + tp * H_DIM];             // refill AFTER write: covers latency
  BARRIER();                             // h' visible
}

__global__ __launch_bounds__(512, 1) void gru_rec8d(
    const float* __restrict__ Uz, const float* __restrict__ Ur, const float* __restrict__ Uh,
    const int* __restrict__ lengths,
    const unsigned int* xzr,            // aliases `out` (packed bf16 xz|xr)
    const unsigned short* __restrict__ xh,
    float* out)
{
  __shared__ __align__(16) __bf16 hx[H_DIM];
  __shared__ __align__(16) __bf16 rhx[H_DIM];

  const int tid = threadIdx.x;
  const int w = tid >> 6, l = tid & 63;
  const int g8 = l >> 4;                // k-slice within each 32-k block
  const int u  = w * 16 + (l & 15);     // owned unit (C col)
  const int b  = blockIdx.x;
  const int len = lengths[b];

  // U B-fragments, prescaled: 3 gates x 4 k-steps x 4 VGPR = 48 VGPRs
  bf16x8 ufz[4], ufr[4], ufh[4];
  #pragma unroll
  for (int kk = 0; kk < 4; ++kk){
    const int ko = kk * 32 + g8 * 8;
    ufz[kk] = ld_u_frag_s(Uz + u * H_DIM + ko, KNEG);
    ufr[kk] = ld_u_frag_s(Ur + u * H_DIM + ko, KNEG);
    ufh[kk] = ld_u_frag_s(Uh + u * H_DIM + ko, KPOS);
  }

  if (tid < 64) reinterpret_cast<unsigned int*>(hx)[tid] = 0u;  // h0 = 0
  float h_own = 0.f;
  __syncthreads();

  const int ub = b * (T_LEN * H_DIM) + u;   // element offset of (b, t=0, u)

  // 6-deep prefetch, named register sets (slots t .. t+5)
  unsigned int  zrA = xzr[ub];
  unsigned int  zrB = xzr[ub + 1 * H_DIM];
  unsigned int  zrC = xzr[ub + 2 * H_DIM];
  unsigned int  zrD = xzr[ub + 3 * H_DIM];
  unsigned int  zrE = xzr[ub + 4 * H_DIM];
  unsigned int  zrF = xzr[ub + 5 * H_DIM];
  unsigned short xhA = xh[ub];
  unsigned short xhB = xh[ub + 1 * H_DIM];
  unsigned short xhC = xh[ub + 2 * H_DIM];
  unsigned short xhD = xh[ub + 3 * H_DIM];
  unsigned short xhE = xh[ub + 4 * H_DIM];
  unsigned short xhF = xh[ub + 5 * H_DIM];

  int t = 0;
  for (; t + 5 < len; t += 6){
    gru_step8(t,   ub, g8, l, w, ufz, ufr, ufh, hx, rhx, xzr, xh, out, zrA, xhA, h_own);
    gru_step8(t+1, ub, g8, l, w, ufz, ufr, ufh, hx, rhx, xzr, xh, out, zrB, xhB, h_own);
    gru_step8(t+2, ub, g8, l, w, ufz, ufr, ufh, hx, rhx, xzr, xh, out, zrC, xhC, h_own);
    gru_step8(t+3, ub, g8, l, w, ufz, ufr, ufh, hx, rhx, xzr, xh, out, zrD, xhD, h_own);
    gru_step8(t+4, ub, g8, l, w, ufz, ufr, ufh, hx, rhx, xzr, xh, out, zrE, xhE, h_own);
    gru_step8(t+5, ub, g8, l, w, ufz, ufr, ufh, hx, rhx, xzr, xh, out, zrF, xhF, h_own);
  }
  if (t < len)
    gru_step8(t,   ub, g8, l, w, ufz, ufr, ufh, hx, rhx, xzr, xh, out, zrA, xhA, h_own);
  if (t + 1 < len)
    gru_step8(t+1, ub, g8, l, w, ufz, ufr, ufh, hx, rhx, xzr, xh, out, zrB, xhB, h_own);
  if (t + 2 < len)
    gru_step8(t+2, ub, g8, l, w, ufz, ufr, ufh, hx, rhx, xzr, xh, out, zrC, xhC, h_own);
  if (t + 3 < len)
    gru_step8(t+3, ub, g8, l, w, ufz, ufr, ufh, hx, rhx, xzr, xh, out, zrD, xhD, h_own);
  if (t + 4 < len)
    gru_step8(t+4, ub, g8, l, w, ufz, ufr, ufh, hx, rhx, xzr, xh, out, zrE, xhE, h_own);

  // masked region: exact zeros for t >= len (disjoint from h-stores)
  const long base = (long)b * (T_LEN * H_DIM);
  for (long i = (long)len * H_DIM + tid * 4; i < (long)T_LEN * H_DIM; i += 512 * 4){
    *reinterpret_cast<float4*>(out + base + i) = make_float4(0.f, 0.f, 0.f, 0.f);
  }
}

extern "C" void kernel_launch(void* const* d_in, const int* in_sizes, int n_in,
                              void* d_out, int out_size, void* d_ws, size_t ws_size,
                              hipStream_t stream){
  const float* x       = (const float*)d_in[0];
  const int*   lengths = (const int*)  d_in[1];
  const float* Wz = (const float*)d_in[2];
  const float* Uz = (const float*)d_in[3];
  const float* bz = (const float*)d_in[4];
  const float* Wr = (const float*)d_in[5];
  const float* Ur = (const float*)d_in[6];
  const float* br = (const float*)d_in[7];
  const float* Wh = (const float*)d_in[8];
  const float* Uh = (const float*)d_in[9];
  const float* bh = (const float*)d_in[10];

  unsigned int*   zr    = (unsigned int*)d_out;   // packed bf16 xz|xr, then h
  unsigned short* xhbuf = (unsigned short*)d_ws;  // bf16 xh

  gru_proj<<<dim3(2048), dim3(512), 0, stream>>>(x, Wz, Wr, Wh, bz, br, bh, zr, xhbuf);
  gru_rec8d<<<dim3(128), dim3(512), 0, stream>>>(Uz, Ur, Uh, lengths, zr, xhbuf, (float*)d_out);
}

// Round 15
// 1009.303 us; speedup vs baseline: 1.2101x; 1.2101x over previous
//
#include <hip/hip_runtime.h>

// GRU: B=128, T=2048, H=128.
// K1 gru_proj: xz/xr/xh = x @ W^T + b via bf16 MFMA. Gate inputs PRESCALED:
//   xz,xr by -log2(e) (sigmoid as rcp(1+exp2(x))), xh by +2*log2(e)
//   (tanh folded into update: hn = A - 2z*rcp(exp2(y)+1)).
// K2 gru_rec8s: R13 structure (1 batch/block x 128 blocks, 8 waves x 16
//   units, broadcast-A MFMA, 4 independent MFMAs/gate + add tree, 2
//   lgkm-only barriers/step, 6-deep prefetch, refill-after-write,
//   fire-and-forget stores) with two critical-path trims:
//   - z-MFMAs issued in PHASE A (r-MFMA latency shadow; land during barrier)
//   - update FMA-fold: A=fma(z,1-h,h), hn=fma(-2z, t, A) -> 1 op after rcp

#define T_LEN 2048
#define H_DIM 128

typedef __attribute__((ext_vector_type(8))) __bf16 bf16x8;
typedef __attribute__((ext_vector_type(4))) float f32x4;

// raw barrier: drains LDS ops (cross-wave visibility) but NOT vmcnt. [m201]
#define BARRIER() asm volatile("s_waitcnt lgkmcnt(0)\n\ts_barrier" ::: "memory")

#define KNEG -1.4426950408889634f   // -log2(e): z,r prescale
#define KPOS  2.8853900817779268f   // 2*log2(e): h prescale

__device__ __forceinline__ unsigned short f2bf_bits(float f){
  __bf16 b = (__bf16)f;                     // fptrunc, RNE
  return __builtin_bit_cast(unsigned short, b);
}
__device__ __forceinline__ float bf2f(unsigned short s){
  unsigned int u = ((unsigned int)s) << 16;
  return __builtin_bit_cast(float, u);
}
// prescaled sigmoid: input already -log2e * logit
__device__ __forceinline__ float sigm_pre(float x){
  return __builtin_amdgcn_rcpf(1.0f + __builtin_amdgcn_exp2f(x));
}

// ---------------- projection GEMM (R1-verified + prescale epilogue) --------

__device__ __forceinline__ void stage_mat128(const float* __restrict__ src,
                                             __bf16 (*dst)[136], int tid){
  #pragma unroll
  for (int rep = 0; rep < 8; ++rep){
    int fi = rep * 2048 + tid * 4;
    float4 v = *reinterpret_cast<const float4*>(src + fi);
    int m = fi >> 7;
    int k = fi & 127;
    unsigned long long pk =
        (unsigned long long)f2bf_bits(v.x)
      | ((unsigned long long)f2bf_bits(v.y) << 16)
      | ((unsigned long long)f2bf_bits(v.z) << 32)
      | ((unsigned long long)f2bf_bits(v.w) << 48);
    *reinterpret_cast<unsigned long long*>(&dst[m][k]) = pk;
  }
}

__global__ __launch_bounds__(512, 2) void gru_proj(
    const float* __restrict__ x,
    const float* __restrict__ Wz, const float* __restrict__ Wr, const float* __restrict__ Wh,
    const float* __restrict__ bz, const float* __restrict__ br, const float* __restrict__ bh,
    unsigned int* __restrict__ out_zr, unsigned short* __restrict__ out_h)
{
  __shared__ __bf16 xs[128][136];
  __shared__ __bf16 wsh[3][128][136];

  const int tid = threadIdx.x;
  const long Mbase = (long)blockIdx.x * 128;

  stage_mat128(x + Mbase * H_DIM, xs, tid);
  stage_mat128(Wz, wsh[0], tid);
  stage_mat128(Wr, wsh[1], tid);
  stage_mat128(Wh, wsh[2], tid);
  __syncthreads();

  const int w  = tid >> 6, l = tid & 63;
  const int ml = l & 15;
  const int kl = (l >> 4) * 8;
  const int n  = w * 16 + ml;

  bf16x8 bfr[3][4];
  #pragma unroll
  for (int g = 0; g < 3; ++g)
    #pragma unroll
    for (int kk = 0; kk < 4; ++kk)
      bfr[g][kk] = *reinterpret_cast<const bf16x8*>(&wsh[g][n][kk * 32 + kl]);

  const float bzv = bz[n], brv = br[n], bhv = bh[n];

  f32x4 acc[8][3];
  #pragma unroll
  for (int mt = 0; mt < 8; ++mt)
    #pragma unroll
    for (int g = 0; g < 3; ++g)
      acc[mt][g] = (f32x4){0.f, 0.f, 0.f, 0.f};

  #pragma unroll
  for (int mt = 0; mt < 8; ++mt){
    #pragma unroll
    for (int kk = 0; kk < 4; ++kk){
      bf16x8 a = *reinterpret_cast<const bf16x8*>(&xs[mt * 16 + ml][kk * 32 + kl]);
      acc[mt][0] = __builtin_amdgcn_mfma_f32_16x16x32_bf16(a, bfr[0][kk], acc[mt][0], 0, 0, 0);
      acc[mt][1] = __builtin_amdgcn_mfma_f32_16x16x32_bf16(a, bfr[1][kk], acc[mt][1], 0, 0, 0);
      acc[mt][2] = __builtin_amdgcn_mfma_f32_16x16x32_bf16(a, bfr[2][kk], acc[mt][2], 0, 0, 0);
    }
  }

  #pragma unroll
  for (int mt = 0; mt < 8; ++mt){
    #pragma unroll
    for (int p = 0; p < 4; ++p){
      long row = Mbase + mt * 16 + (l >> 4) * 4 + p;
      float vz = (acc[mt][0][p] + bzv) * KNEG;   // prescaled for sigm_pre
      float vr = (acc[mt][1][p] + brv) * KNEG;
      float vh = (acc[mt][2][p] + bhv) * KPOS;   // prescaled for folded tanh
      unsigned int word = (unsigned int)f2bf_bits(vz)
                        | (((unsigned int)f2bf_bits(vr)) << 16);
      out_zr[row * H_DIM + n] = word;
      out_h [row * H_DIM + n] = f2bf_bits(vh);
    }
  }
}

// -------- recurrence: broadcast-A MFMA, 8 waves, 6-deep prefetch ------------

__device__ __forceinline__ bf16x8 ld_u_frag_s(const float* p, float s){
  float4 a = *reinterpret_cast<const float4*>(p);
  float4 b = *reinterpret_cast<const float4*>(p + 4);
  bf16x8 r;
  r[0]=(__bf16)(a.x*s); r[1]=(__bf16)(a.y*s); r[2]=(__bf16)(a.z*s); r[3]=(__bf16)(a.w*s);
  r[4]=(__bf16)(b.x*s); r[5]=(__bf16)(b.y*s); r[6]=(__bf16)(b.z*s); r[7]=(__bf16)(b.w*s);
  return r;
}

#define MFMA(A, B, C) __builtin_amdgcn_mfma_f32_16x16x32_bf16(A, B, C, 0, 0, 0)

__device__ __forceinline__ void gru_step8(
    int t, int ub, int g8, int l, int w,
    const bf16x8* ufz, const bf16x8* ufr, const bf16x8* ufh,
    __bf16* hx, __bf16* rhx,
    const unsigned int* xzr, const unsigned short* xh, float* out,
    unsigned int& zrw, unsigned short& xhw, float& h_own, float& one_m_h)
{
  const f32x4 zero = (f32x4){0.f, 0.f, 0.f, 0.f};
  const int tp = (t + 6 < T_LEN) ? t + 6 : T_LEN - 1;   // 6-deep refill slot
  const int u  = w * 16 + (l & 15);
  const bool own = (l < 16);

  // ---- phase A: r gate; z-MFMAs issued in the r latency shadow ----
  bf16x8 a0 = *reinterpret_cast<const bf16x8*>(&hx[      g8 * 8]);
  bf16x8 a1 = *reinterpret_cast<const bf16x8*>(&hx[32  + g8 * 8]);
  bf16x8 a2 = *reinterpret_cast<const bf16x8*>(&hx[64  + g8 * 8]);
  bf16x8 a3 = *reinterpret_cast<const bf16x8*>(&hx[96  + g8 * 8]);
  f32x4 r0 = MFMA(a0, ufr[0], zero);
  f32x4 r1 = MFMA(a1, ufr[1], zero);
  f32x4 r2 = MFMA(a2, ufr[2], zero);
  f32x4 r3 = MFMA(a3, ufr[3], zero);
  f32x4 z0 = MFMA(a0, ufz[0], zero);    // land during barrier; used phase B
  f32x4 z1 = MFMA(a1, ufz[1], zero);
  f32x4 z2 = MFMA(a2, ufz[2], zero);
  f32x4 z3 = MFMA(a3, ufz[3], zero);

  // consume this step's prefetched inputs (pre-refill)
  float xzv = bf2f((unsigned short)(zrw & 0xffffu));
  float xrv = bf2f((unsigned short)(zrw >> 16));
  float xhv = bf2f(xhw);

  float rg = sigm_pre(xrv + ((r0[0] + r1[0]) + (r2[0] + r3[0])));
  float rh = rg * h_own;
  if (own)
    rhx[u] = (__bf16)rh;                 // b16, 2 lanes/dword: conflict-free
  zrw = xzr[ub + tp * H_DIM];            // refill AFTER write: covers latency
  BARRIER();                             // rh visible

  // ---- phase B: zg immediately; h~ MFMAs; folded update ----
  bf16x8 b0 = *reinterpret_cast<const bf16x8*>(&rhx[      g8 * 8]);
  bf16x8 b1 = *reinterpret_cast<const bf16x8*>(&rhx[32  + g8 * 8]);
  bf16x8 b2 = *reinterpret_cast<const bf16x8*>(&rhx[64  + g8 * 8]);
  bf16x8 b3 = *reinterpret_cast<const bf16x8*>(&rhx[96  + g8 * 8]);

  float zg = sigm_pre(xzv + ((z0[0] + z1[0]) + (z2[0] + z3[0])));
  float Au = fmaf(zg, one_m_h, h_own);   // h + z*(1-h), ready before rcp
  float Bu = -2.0f * zg;

  f32x4 h0 = MFMA(b0, ufh[0], zero);
  f32x4 h1 = MFMA(b1, ufh[1], zero);
  f32x4 h2 = MFMA(b2, ufh[2], zero);
  f32x4 h3 = MFMA(b3, ufh[3], zero);

  float th = __builtin_amdgcn_rcpf(
      __builtin_amdgcn_exp2f(xhv + ((h0[0] + h1[0]) + (h2[0] + h3[0]))) + 1.0f);
  float hn = fmaf(Bu, th, Au);           // hn = A - 2z*th  (== (1-z)h + z*hc)
  h_own = hn;
  one_m_h = 1.0f - hn;                   // off-path, for next step
  if (own){
    hx[u] = (__bf16)hn;
    out[ub + t * H_DIM] = hn;            // fire-and-forget
  }
  xhw = xh[ub + tp * H_DIM];             // refill AFTER write: covers latency
  BARRIER();                             // h' visible
}

__global__ __launch_bounds__(512, 1) void gru_rec8s(
    const float* __restrict__ Uz, const float* __restrict__ Ur, const float* __restrict__ Uh,
    const int* __restrict__ lengths,
    const unsigned int* xzr,            // aliases `out` (packed bf16 xz|xr)
    const unsigned short* __restrict__ xh,
    float* out)
{
  __shared__ __align__(16) __bf16 hx[H_DIM];
  __shared__ __align__(16) __bf16 rhx[H_DIM];

  const int tid = threadIdx.x;
  const int w = tid >> 6, l = tid & 63;
  const int g8 = l >> 4;                // k-slice within each 32-k block
  const int u  = w * 16 + (l & 15);     // owned unit (C col)
  const int b  = blockIdx.x;
  const int len = lengths[b];

  // U B-fragments, prescaled: 3 gates x 4 k-steps x 4 VGPR = 48 VGPRs
  bf16x8 ufz[4], ufr[4], ufh[4];
  #pragma unroll
  for (int kk = 0; kk < 4; ++kk){
    const int ko = kk * 32 + g8 * 8;
    ufz[kk] = ld_u_frag_s(Uz + u * H_DIM + ko, KNEG);
    ufr[kk] = ld_u_frag_s(Ur + u * H_DIM + ko, KNEG);
    ufh[kk] = ld_u_frag_s(Uh + u * H_DIM + ko, KPOS);
  }

  if (tid < 64) reinterpret_cast<unsigned int*>(hx)[tid] = 0u;  // h0 = 0
  float h_own = 0.f, one_m_h = 1.f;
  __syncthreads();

  const int ub = b * (T_LEN * H_DIM) + u;   // element offset of (b, t=0, u)

  // 6-deep prefetch, named register sets (slots t .. t+5)
  unsigned int  zrA = xzr[ub];
  unsigned int  zrB = xzr[ub + 1 * H_DIM];
  unsigned int  zrC = xzr[ub + 2 * H_DIM];
  unsigned int  zrD = xzr[ub + 3 * H_DIM];
  unsigned int  zrE = xzr[ub + 4 * H_DIM];
  unsigned int  zrF = xzr[ub + 5 * H_DIM];
  unsigned short xhA = xh[ub];
  unsigned short xhB = xh[ub + 1 * H_DIM];
  unsigned short xhC = xh[ub + 2 * H_DIM];
  unsigned short xhD = xh[ub + 3 * H_DIM];
  unsigned short xhE = xh[ub + 4 * H_DIM];
  unsigned short xhF = xh[ub + 5 * H_DIM];

  int t = 0;
  for (; t + 5 < len; t += 6){
    gru_step8(t,   ub, g8, l, w, ufz, ufr, ufh, hx, rhx, xzr, xh, out, zrA, xhA, h_own, one_m_h);
    gru_step8(t+1, ub, g8, l, w, ufz, ufr, ufh, hx, rhx, xzr, xh, out, zrB, xhB, h_own, one_m_h);
    gru_step8(t+2, ub, g8, l, w, ufz, ufr, ufh, hx, rhx, xzr, xh, out, zrC, xhC, h_own, one_m_h);
    gru_step8(t+3, ub, g8, l, w, ufz, ufr, ufh, hx, rhx, xzr, xh, out, zrD, xhD, h_own, one_m_h);
    gru_step8(t+4, ub, g8, l, w, ufz, ufr, ufh, hx, rhx, xzr, xh, out, zrE, xhE, h_own, one_m_h);
    gru_step8(t+5, ub, g8, l, w, ufz, ufr, ufh, hx, rhx, xzr, xh, out, zrF, xhF, h_own, one_m_h);
  }
  if (t < len)
    gru_step8(t,   ub, g8, l, w, ufz, ufr, ufh, hx, rhx, xzr, xh, out, zrA, xhA, h_own, one_m_h);
  if (t + 1 < len)
    gru_step8(t+1, ub, g8, l, w, ufz, ufr, ufh, hx, rhx, xzr, xh, out, zrB, xhB, h_own, one_m_h);
  if (t + 2 < len)
    gru_step8(t+2, ub, g8, l, w, ufz, ufr, ufh, hx, rhx, xzr, xh, out, zrC, xhC, h_own, one_m_h);
  if (t + 3 < len)
    gru_step8(t+3, ub, g8, l, w, ufz, ufr, ufh, hx, rhx, xzr, xh, out, zrD, xhD, h_own, one_m_h);
  if (t + 4 < len)
    gru_step8(t+4, ub, g8, l, w, ufz, ufr, ufh, hx, rhx, xzr, xh, out, zrE, xhE, h_own, one_m_h);

  // masked region: exact zeros for t >= len (disjoint from h-stores)
  const long base = (long)b * (T_LEN * H_DIM);
  for (long i = (long)len * H_DIM + tid * 4; i < (long)T_LEN * H_DIM; i += 512 * 4){
    *reinterpret_cast<float4*>(out + base + i) = make_float4(0.f, 0.f, 0.f, 0.f);
  }
}

extern "C" void kernel_launch(void* const* d_in, const int* in_sizes, int n_in,
                              void* d_out, int out_size, void* d_ws, size_t ws_size,
                              hipStream_t stream){
  const float* x       = (const float*)d_in[0];
  const int*   lengths = (const int*)  d_in[1];
  const float* Wz = (const float*)d_in[2];
  const float* Uz = (const float*)d_in[3];
  const float* bz = (const float*)d_in[4];
  const float* Wr = (const float*)d_in[5];
  const float* Ur = (const float*)d_in[6];
  const float* br = (const float*)d_in[7];
  const float* Wh = (const float*)d_in[8];
  const float* Uh = (const float*)d_in[9];
  const float* bh = (const float*)d_in[10];

  unsigned int*   zr    = (unsigned int*)d_out;   // packed bf16 xz|xr, then h
  unsigned short* xhbuf = (unsigned short*)d_ws;  // bf16 xh

  gru_proj<<<dim3(2048), dim3(512), 0, stream>>>(x, Wz, Wr, Wh, bz, br, bh, zr, xhbuf);
  gru_rec8s<<<dim3(128), dim3(512), 0, stream>>>(Uz, Ur, Uh, lengths, zr, xhbuf, (float*)d_out);
}

// Round 16
// 988.660 us; speedup vs baseline: 1.2354x; 1.0209x over previous
//
#include <hip/hip_runtime.h>

// GRU: B=128, T=2048, H=128.
// K1 gru_proj: xz/xr/xh = x @ W^T + b via bf16 MFMA. Gate inputs PRESCALED:
//   xz,xr by -log2(e) (sigmoid as rcp(1+exp2(x))), xh by +2*log2(e)
//   (tanh folded into update: hn = A - 2z*rcp(exp2(y)+1)).
// K2 gru_rec8f: EXACT R13 structure (1 batch/block x 128 blocks, 8 waves x
//   16 units, broadcast-A MFMA, 4 independent MFMAs/gate + add tree,
//   z-MFMAs in PHASE B issued before rh-read data lands, 2 lgkm-only
//   barriers/step, 6-deep prefetch, refill-after-write, fire-and-forget
//   stores) + FMA-folded update only (post-rcp chain 3 ops -> 1).
//   R15 lesson: never add issue work ahead of the exchange writes.

#define T_LEN 2048
#define H_DIM 128

typedef __attribute__((ext_vector_type(8))) __bf16 bf16x8;
typedef __attribute__((ext_vector_type(4))) float f32x4;

// raw barrier: drains LDS ops (cross-wave visibility) but NOT vmcnt. [m201]
#define BARRIER() asm volatile("s_waitcnt lgkmcnt(0)\n\ts_barrier" ::: "memory")

#define KNEG -1.4426950408889634f   // -log2(e): z,r prescale
#define KPOS  2.8853900817779268f   // 2*log2(e): h prescale

__device__ __forceinline__ unsigned short f2bf_bits(float f){
  __bf16 b = (__bf16)f;                     // fptrunc, RNE
  return __builtin_bit_cast(unsigned short, b);
}
__device__ __forceinline__ float bf2f(unsigned short s){
  unsigned int u = ((unsigned int)s) << 16;
  return __builtin_bit_cast(float, u);
}
// prescaled sigmoid: input already -log2e * logit
__device__ __forceinline__ float sigm_pre(float x){
  return __builtin_amdgcn_rcpf(1.0f + __builtin_amdgcn_exp2f(x));
}

// ---------------- projection GEMM (R1-verified + prescale epilogue) --------

__device__ __forceinline__ void stage_mat128(const float* __restrict__ src,
                                             __bf16 (*dst)[136], int tid){
  #pragma unroll
  for (int rep = 0; rep < 8; ++rep){
    int fi = rep * 2048 + tid * 4;
    float4 v = *reinterpret_cast<const float4*>(src + fi);
    int m = fi >> 7;
    int k = fi & 127;
    unsigned long long pk =
        (unsigned long long)f2bf_bits(v.x)
      | ((unsigned long long)f2bf_bits(v.y) << 16)
      | ((unsigned long long)f2bf_bits(v.z) << 32)
      | ((unsigned long long)f2bf_bits(v.w) << 48);
    *reinterpret_cast<unsigned long long*>(&dst[m][k]) = pk;
  }
}

__global__ __launch_bounds__(512, 2) void gru_proj(
    const float* __restrict__ x,
    const float* __restrict__ Wz, const float* __restrict__ Wr, const float* __restrict__ Wh,
    const float* __restrict__ bz, const float* __restrict__ br, const float* __restrict__ bh,
    unsigned int* __restrict__ out_zr, unsigned short* __restrict__ out_h)
{
  __shared__ __bf16 xs[128][136];
  __shared__ __bf16 wsh[3][128][136];

  const int tid = threadIdx.x;
  const long Mbase = (long)blockIdx.x * 128;

  stage_mat128(x + Mbase * H_DIM, xs, tid);
  stage_mat128(Wz, wsh[0], tid);
  stage_mat128(Wr, wsh[1], tid);
  stage_mat128(Wh, wsh[2], tid);
  __syncthreads();

  const int w  = tid >> 6, l = tid & 63;
  const int ml = l & 15;
  const int kl = (l >> 4) * 8;
  const int n  = w * 16 + ml;

  bf16x8 bfr[3][4];
  #pragma unroll
  for (int g = 0; g < 3; ++g)
    #pragma unroll
    for (int kk = 0; kk < 4; ++kk)
      bfr[g][kk] = *reinterpret_cast<const bf16x8*>(&wsh[g][n][kk * 32 + kl]);

  const float bzv = bz[n], brv = br[n], bhv = bh[n];

  f32x4 acc[8][3];
  #pragma unroll
  for (int mt = 0; mt < 8; ++mt)
    #pragma unroll
    for (int g = 0; g < 3; ++g)
      acc[mt][g] = (f32x4){0.f, 0.f, 0.f, 0.f};

  #pragma unroll
  for (int mt = 0; mt < 8; ++mt){
    #pragma unroll
    for (int kk = 0; kk < 4; ++kk){
      bf16x8 a = *reinterpret_cast<const bf16x8*>(&xs[mt * 16 + ml][kk * 32 + kl]);
      acc[mt][0] = __builtin_amdgcn_mfma_f32_16x16x32_bf16(a, bfr[0][kk], acc[mt][0], 0, 0, 0);
      acc[mt][1] = __builtin_amdgcn_mfma_f32_16x16x32_bf16(a, bfr[1][kk], acc[mt][1], 0, 0, 0);
      acc[mt][2] = __builtin_amdgcn_mfma_f32_16x16x32_bf16(a, bfr[2][kk], acc[mt][2], 0, 0, 0);
    }
  }

  #pragma unroll
  for (int mt = 0; mt < 8; ++mt){
    #pragma unroll
    for (int p = 0; p < 4; ++p){
      long row = Mbase + mt * 16 + (l >> 4) * 4 + p;
      float vz = (acc[mt][0][p] + bzv) * KNEG;   // prescaled for sigm_pre
      float vr = (acc[mt][1][p] + brv) * KNEG;
      float vh = (acc[mt][2][p] + bhv) * KPOS;   // prescaled for folded tanh
      unsigned int word = (unsigned int)f2bf_bits(vz)
                        | (((unsigned int)f2bf_bits(vr)) << 16);
      out_zr[row * H_DIM + n] = word;
      out_h [row * H_DIM + n] = f2bf_bits(vh);
    }
  }
}

// -------- recurrence: broadcast-A MFMA, 8 waves, 6-deep prefetch ------------

__device__ __forceinline__ bf16x8 ld_u_frag_s(const float* p, float s){
  float4 a = *reinterpret_cast<const float4*>(p);
  float4 b = *reinterpret_cast<const float4*>(p + 4);
  bf16x8 r;
  r[0]=(__bf16)(a.x*s); r[1]=(__bf16)(a.y*s); r[2]=(__bf16)(a.z*s); r[3]=(__bf16)(a.w*s);
  r[4]=(__bf16)(b.x*s); r[5]=(__bf16)(b.y*s); r[6]=(__bf16)(b.z*s); r[7]=(__bf16)(b.w*s);
  return r;
}

#define MFMA(A, B, C) __builtin_amdgcn_mfma_f32_16x16x32_bf16(A, B, C, 0, 0, 0)

__device__ __forceinline__ void gru_step8(
    int t, int ub, int g8, int l, int w,
    const bf16x8* ufz, const bf16x8* ufr, const bf16x8* ufh,
    __bf16* hx, __bf16* rhx,
    const unsigned int* xzr, const unsigned short* xh, float* out,
    unsigned int& zrw, unsigned short& xhw, float& h_own, float& one_m_h)
{
  const f32x4 zero = (f32x4){0.f, 0.f, 0.f, 0.f};
  const int tp = (t + 6 < T_LEN) ? t + 6 : T_LEN - 1;   // 6-deep refill slot
  const int u  = w * 16 + (l & 15);
  const bool own = (l < 16);

  // ---- phase A: r gate ONLY ahead of the rh write (R13 discipline) ----
  bf16x8 a0 = *reinterpret_cast<const bf16x8*>(&hx[      g8 * 8]);
  bf16x8 a1 = *reinterpret_cast<const bf16x8*>(&hx[32  + g8 * 8]);
  bf16x8 a2 = *reinterpret_cast<const bf16x8*>(&hx[64  + g8 * 8]);
  bf16x8 a3 = *reinterpret_cast<const bf16x8*>(&hx[96  + g8 * 8]);
  f32x4 r0 = MFMA(a0, ufr[0], zero);
  f32x4 r1 = MFMA(a1, ufr[1], zero);
  f32x4 r2 = MFMA(a2, ufr[2], zero);
  f32x4 r3 = MFMA(a3, ufr[3], zero);

  // consume this step's prefetched inputs (pre-refill)
  float xzv = bf2f((unsigned short)(zrw & 0xffffu));
  float xrv = bf2f((unsigned short)(zrw >> 16));
  float xhv = bf2f(xhw);

  float rg = sigm_pre(xrv + ((r0[0] + r1[0]) + (r2[0] + r3[0])));
  float rh = rg * h_own;
  if (own)
    rhx[u] = (__bf16)rh;                 // b16, 2 lanes/dword: conflict-free
  zrw = xzr[ub + tp * H_DIM];            // refill AFTER write: covers latency
  BARRIER();                             // rh visible

  // ---- phase B: z on register h-frags (overlaps rh read) + h~ + update ----
  bf16x8 b0 = *reinterpret_cast<const bf16x8*>(&rhx[      g8 * 8]);
  bf16x8 b1 = *reinterpret_cast<const bf16x8*>(&rhx[32  + g8 * 8]);
  bf16x8 b2 = *reinterpret_cast<const bf16x8*>(&rhx[64  + g8 * 8]);
  bf16x8 b3 = *reinterpret_cast<const bf16x8*>(&rhx[96  + g8 * 8]);
  f32x4 z0 = MFMA(a0, ufz[0], zero);     // register inputs: issue under read
  f32x4 z1 = MFMA(a1, ufz[1], zero);
  f32x4 z2 = MFMA(a2, ufz[2], zero);
  f32x4 z3 = MFMA(a3, ufz[3], zero);
  f32x4 h0 = MFMA(b0, ufh[0], zero);
  f32x4 h1 = MFMA(b1, ufh[1], zero);
  f32x4 h2 = MFMA(b2, ufh[2], zero);
  f32x4 h3 = MFMA(b3, ufh[3], zero);

  float zg = sigm_pre(xzv + ((z0[0] + z1[0]) + (z2[0] + z3[0])));
  float Au = fmaf(zg, one_m_h, h_own);   // h + z*(1-h), ready before rcp
  float Bu = -2.0f * zg;
  float th = __builtin_amdgcn_rcpf(
      __builtin_amdgcn_exp2f(xhv + ((h0[0] + h1[0]) + (h2[0] + h3[0]))) + 1.0f);
  float hn = fmaf(Bu, th, Au);           // hn = A - 2z*th  (== (1-z)h + z*hc)
  h_own = hn;
  one_m_h = 1.0f - hn;                   // off-path, for next step
  if (own){
    hx[u] = (__bf16)hn;
    out[ub + t * H_DIM] = hn;            // fire-and-forget
  }
  xhw = xh[ub + tp * H_DIM];             // refill AFTER write: covers latency
  BARRIER();                             // h' visible
}

__global__ __launch_bounds__(512, 1) void gru_rec8f(
    const float* __restrict__ Uz, const float* __restrict__ Ur, const float* __restrict__ Uh,
    const int* __restrict__ lengths,
    const unsigned int* xzr,            // aliases `out` (packed bf16 xz|xr)
    const unsigned short* __restrict__ xh,
    float* out)
{
  __shared__ __align__(16) __bf16 hx[H_DIM];
  __shared__ __align__(16) __bf16 rhx[H_DIM];

  const int tid = threadIdx.x;
  const int w = tid >> 6, l = tid & 63;
  const int g8 = l >> 4;                // k-slice within each 32-k block
  const int u  = w * 16 + (l & 15);     // owned unit (C col)
  const int b  = blockIdx.x;
  const int len = lengths[b];

  // U B-fragments, prescaled: 3 gates x 4 k-steps x 4 VGPR = 48 VGPRs
  bf16x8 ufz[4], ufr[4], ufh[4];
  #pragma unroll
  for (int kk = 0; kk < 4; ++kk){
    const int ko = kk * 32 + g8 * 8;
    ufz[kk] = ld_u_frag_s(Uz + u * H_DIM + ko, KNEG);
    ufr[kk] = ld_u_frag_s(Ur + u * H_DIM + ko, KNEG);
    ufh[kk] = ld_u_frag_s(Uh + u * H_DIM + ko, KPOS);
  }

  if (tid < 64) reinterpret_cast<unsigned int*>(hx)[tid] = 0u;  // h0 = 0
  float h_own = 0.f, one_m_h = 1.f;
  __syncthreads();

  const int ub = b * (T_LEN * H_DIM) + u;   // element offset of (b, t=0, u)

  // 6-deep prefetch, named register sets (slots t .. t+5)
  unsigned int  zrA = xzr[ub];
  unsigned int  zrB = xzr[ub + 1 * H_DIM];
  unsigned int  zrC = xzr[ub + 2 * H_DIM];
  unsigned int  zrD = xzr[ub + 3 * H_DIM];
  unsigned int  zrE = xzr[ub + 4 * H_DIM];
  unsigned int  zrF = xzr[ub + 5 * H_DIM];
  unsigned short xhA = xh[ub];
  unsigned short xhB = xh[ub + 1 * H_DIM];
  unsigned short xhC = xh[ub + 2 * H_DIM];
  unsigned short xhD = xh[ub + 3 * H_DIM];
  unsigned short xhE = xh[ub + 4 * H_DIM];
  unsigned short xhF = xh[ub + 5 * H_DIM];

  int t = 0;
  for (; t + 5 < len; t += 6){
    gru_step8(t,   ub, g8, l, w, ufz, ufr, ufh, hx, rhx, xzr, xh, out, zrA, xhA, h_own, one_m_h);
    gru_step8(t+1, ub, g8, l, w, ufz, ufr, ufh, hx, rhx, xzr, xh, out, zrB, xhB, h_own, one_m_h);
    gru_step8(t+2, ub, g8, l, w, ufz, ufr, ufh, hx, rhx, xzr, xh, out, zrC, xhC, h_own, one_m_h);
    gru_step8(t+3, ub, g8, l, w, ufz, ufr, ufh, hx, rhx, xzr, xh, out, zrD, xhD, h_own, one_m_h);
    gru_step8(t+4, ub, g8, l, w, ufz, ufr, ufh, hx, rhx, xzr, xh, out, zrE, xhE, h_own, one_m_h);
    gru_step8(t+5, ub, g8, l, w, ufz, ufr, ufh, hx, rhx, xzr, xh, out, zrF, xhF, h_own, one_m_h);
  }
  if (t < len)
    gru_step8(t,   ub, g8, l, w, ufz, ufr, ufh, hx, rhx, xzr, xh, out, zrA, xhA, h_own, one_m_h);
  if (t + 1 < len)
    gru_step8(t+1, ub, g8, l, w, ufz, ufr, ufh, hx, rhx, xzr, xh, out, zrB, xhB, h_own, one_m_h);
  if (t + 2 < len)
    gru_step8(t+2, ub, g8, l, w, ufz, ufr, ufh, hx, rhx, xzr, xh, out, zrC, xhC, h_own, one_m_h);
  if (t + 3 < len)
    gru_step8(t+3, ub, g8, l, w, ufz, ufr, ufh, hx, rhx, xzr, xh, out, zrD, xhD, h_own, one_m_h);
  if (t + 4 < len)
    gru_step8(t+4, ub, g8, l, w, ufz, ufr, ufh, hx, rhx, xzr, xh, out, zrE, xhE, h_own, one_m_h);

  // masked region: exact zeros for t >= len (disjoint from h-stores)
  const long base = (long)b * (T_LEN * H_DIM);
  for (long i = (long)len * H_DIM + tid * 4; i < (long)T_LEN * H_DIM; i += 512 * 4){
    *reinterpret_cast<float4*>(out + base + i) = make_float4(0.f, 0.f, 0.f, 0.f);
  }
}

extern "C" void kernel_launch(void* const* d_in, const int* in_sizes, int n_in,
                              void* d_out, int out_size, void* d_ws, size_t ws_size,
                              hipStream_t stream){
  const float* x       = (const float*)d_in[0];
  const int*   lengths = (const int*)  d_in[1];
  const float* Wz = (const float*)d_in[2];
  const float* Uz = (const float*)d_in[3];
  const float* bz = (const float*)d_in[4];
  const float* Wr = (const float*)d_in[5];
  const float* Ur = (const float*)d_in[6];
  const float* br = (const float*)d_in[7];
  const float* Wh = (const float*)d_in[8];
  const float* Uh = (const float*)d_in[9];
  const float* bh = (const float*)d_in[10];

  unsigned int*   zr    = (unsigned int*)d_out;   // packed bf16 xz|xr, then h
  unsigned short* xhbuf = (unsigned short*)d_ws;  // bf16 xh

  gru_proj<<<dim3(2048), dim3(512), 0, stream>>>(x, Wz, Wr, Wh, bz, br, bh, zr, xhbuf);
  gru_rec8f<<<dim3(128), dim3(512), 0, stream>>>(Uz, Ur, Uh, lengths, zr, xhbuf, (float*)d_out);
}

// Round 17
// 969.484 us; speedup vs baseline: 1.2598x; 1.0198x over previous
//
#include <hip/hip_runtime.h>

// GRU: B=128, T=2048, H=128.  FINAL: exact R13 (best measured: 972 us total).
// K1 gru_proj: xz/xr/xh = x @ W^T + b via bf16 MFMA. Gate inputs PRESCALED:
//   xz,xr by -log2(e) (sigmoid as rcp(1+exp2(x))), xh by +2*log2(e)
//   (tanh as fma(-2, rcp(exp2(y)+1), 1)). U-frags likewise scaled at load.
// K2 gru_rec8q: 1 batch/block x 128 blocks, 8 waves x 16 units, broadcast-A
//   MFMA (k-reduce inside MFMA), 4 independent MFMAs/gate + add tree,
//   z-MFMAs issued in phase B before rh-read data lands (free overlap),
//   2 lgkm-only barriers/step (vmcnt never drained), 6-deep named-register
//   global prefetch, refills issued AFTER each phase's LDS write,
//   direct exec-masked ds_write_b16 exchange, fire-and-forget h stores.
// Structural floor: 2 serial cross-wave exchanges/step x 2048 steps
// (latency-bound; VALU/MFMA/HBM all <11% busy).

#define T_LEN 2048
#define H_DIM 128

typedef __attribute__((ext_vector_type(8))) __bf16 bf16x8;
typedef __attribute__((ext_vector_type(4))) float f32x4;

// raw barrier: drains LDS ops (cross-wave visibility) but NOT vmcnt. [m201]
#define BARRIER() asm volatile("s_waitcnt lgkmcnt(0)\n\ts_barrier" ::: "memory")

#define KNEG -1.4426950408889634f   // -log2(e): z,r prescale
#define KPOS  2.8853900817779268f   // 2*log2(e): h prescale

__device__ __forceinline__ unsigned short f2bf_bits(float f){
  __bf16 b = (__bf16)f;                     // fptrunc, RNE
  return __builtin_bit_cast(unsigned short, b);
}
__device__ __forceinline__ float bf2f(unsigned short s){
  unsigned int u = ((unsigned int)s) << 16;
  return __builtin_bit_cast(float, u);
}
// prescaled sigmoid: input already -log2e * logit
__device__ __forceinline__ float sigm_pre(float x){
  return __builtin_amdgcn_rcpf(1.0f + __builtin_amdgcn_exp2f(x));
}
// prescaled tanh: input already 2*log2e * arg
__device__ __forceinline__ float tanh_pre(float y){
  float t = __builtin_amdgcn_rcpf(__builtin_amdgcn_exp2f(y) + 1.0f);
  return fmaf(-2.0f, t, 1.0f);              // inf-safe: ->1 / ->-1
}

// ---------------- projection GEMM (R1-verified + prescale epilogue) --------

__device__ __forceinline__ void stage_mat128(const float* __restrict__ src,
                                             __bf16 (*dst)[136], int tid){
  #pragma unroll
  for (int rep = 0; rep < 8; ++rep){
    int fi = rep * 2048 + tid * 4;
    float4 v = *reinterpret_cast<const float4*>(src + fi);
    int m = fi >> 7;
    int k = fi & 127;
    unsigned long long pk =
        (unsigned long long)f2bf_bits(v.x)
      | ((unsigned long long)f2bf_bits(v.y) << 16)
      | ((unsigned long long)f2bf_bits(v.z) << 32)
      | ((unsigned long long)f2bf_bits(v.w) << 48);
    *reinterpret_cast<unsigned long long*>(&dst[m][k]) = pk;
  }
}

__global__ __launch_bounds__(512, 2) void gru_proj(
    const float* __restrict__ x,
    const float* __restrict__ Wz, const float* __restrict__ Wr, const float* __restrict__ Wh,
    const float* __restrict__ bz, const float* __restrict__ br, const float* __restrict__ bh,
    unsigned int* __restrict__ out_zr, unsigned short* __restrict__ out_h)
{
  __shared__ __bf16 xs[128][136];
  __shared__ __bf16 wsh[3][128][136];

  const int tid = threadIdx.x;
  const long Mbase = (long)blockIdx.x * 128;

  stage_mat128(x + Mbase * H_DIM, xs, tid);
  stage_mat128(Wz, wsh[0], tid);
  stage_mat128(Wr, wsh[1], tid);
  stage_mat128(Wh, wsh[2], tid);
  __syncthreads();

  const int w  = tid >> 6, l = tid & 63;
  const int ml = l & 15;
  const int kl = (l >> 4) * 8;
  const int n  = w * 16 + ml;

  bf16x8 bfr[3][4];
  #pragma unroll
  for (int g = 0; g < 3; ++g)
    #pragma unroll
    for (int kk = 0; kk < 4; ++kk)
      bfr[g][kk] = *reinterpret_cast<const bf16x8*>(&wsh[g][n][kk * 32 + kl]);

  const float bzv = bz[n], brv = br[n], bhv = bh[n];

  f32x4 acc[8][3];
  #pragma unroll
  for (int mt = 0; mt < 8; ++mt)
    #pragma unroll
    for (int g = 0; g < 3; ++g)
      acc[mt][g] = (f32x4){0.f, 0.f, 0.f, 0.f};

  #pragma unroll
  for (int mt = 0; mt < 8; ++mt){
    #pragma unroll
    for (int kk = 0; kk < 4; ++kk){
      bf16x8 a = *reinterpret_cast<const bf16x8*>(&xs[mt * 16 + ml][kk * 32 + kl]);
      acc[mt][0] = __builtin_amdgcn_mfma_f32_16x16x32_bf16(a, bfr[0][kk], acc[mt][0], 0, 0, 0);
      acc[mt][1] = __builtin_amdgcn_mfma_f32_16x16x32_bf16(a, bfr[1][kk], acc[mt][1], 0, 0, 0);
      acc[mt][2] = __builtin_amdgcn_mfma_f32_16x16x32_bf16(a, bfr[2][kk], acc[mt][2], 0, 0, 0);
    }
  }

  #pragma unroll
  for (int mt = 0; mt < 8; ++mt){
    #pragma unroll
    for (int p = 0; p < 4; ++p){
      long row = Mbase + mt * 16 + (l >> 4) * 4 + p;
      float vz = (acc[mt][0][p] + bzv) * KNEG;   // prescaled for sigm_pre
      float vr = (acc[mt][1][p] + brv) * KNEG;
      float vh = (acc[mt][2][p] + bhv) * KPOS;   // prescaled for tanh_pre
      unsigned int word = (unsigned int)f2bf_bits(vz)
                        | (((unsigned int)f2bf_bits(vr)) << 16);
      out_zr[row * H_DIM + n] = word;
      out_h [row * H_DIM + n] = f2bf_bits(vh);
    }
  }
}

// -------- recurrence: broadcast-A MFMA, 8 waves, 6-deep prefetch ------------

__device__ __forceinline__ bf16x8 ld_u_frag_s(const float* p, float s){
  float4 a = *reinterpret_cast<const float4*>(p);
  float4 b = *reinterpret_cast<const float4*>(p + 4);
  bf16x8 r;
  r[0]=(__bf16)(a.x*s); r[1]=(__bf16)(a.y*s); r[2]=(__bf16)(a.z*s); r[3]=(__bf16)(a.w*s);
  r[4]=(__bf16)(b.x*s); r[5]=(__bf16)(b.y*s); r[6]=(__bf16)(b.z*s); r[7]=(__bf16)(b.w*s);
  return r;
}

#define MFMA(A, B, C) __builtin_amdgcn_mfma_f32_16x16x32_bf16(A, B, C, 0, 0, 0)

__device__ __forceinline__ void gru_step8(
    int t, int ub, int g8, int l, int w,
    const bf16x8* ufz, const bf16x8* ufr, const bf16x8* ufh,
    __bf16* hx, __bf16* rhx,
    const unsigned int* xzr, const unsigned short* xh, float* out,
    unsigned int& zrw, unsigned short& xhw, float& h_own)
{
  const f32x4 zero = (f32x4){0.f, 0.f, 0.f, 0.f};
  const int tp = (t + 6 < T_LEN) ? t + 6 : T_LEN - 1;   // 6-deep refill slot
  const int u  = w * 16 + (l & 15);
  const bool own = (l < 16);

  // ---- phase A: r gate only; 4 independent MFMAs + add tree ----
  bf16x8 a0 = *reinterpret_cast<const bf16x8*>(&hx[      g8 * 8]);
  bf16x8 a1 = *reinterpret_cast<const bf16x8*>(&hx[32  + g8 * 8]);
  bf16x8 a2 = *reinterpret_cast<const bf16x8*>(&hx[64  + g8 * 8]);
  bf16x8 a3 = *reinterpret_cast<const bf16x8*>(&hx[96  + g8 * 8]);
  f32x4 r0 = MFMA(a0, ufr[0], zero);
  f32x4 r1 = MFMA(a1, ufr[1], zero);
  f32x4 r2 = MFMA(a2, ufr[2], zero);
  f32x4 r3 = MFMA(a3, ufr[3], zero);

  // consume this step's prefetched inputs (pre-refill)
  float xzv = bf2f((unsigned short)(zrw & 0xffffu));
  float xrv = bf2f((unsigned short)(zrw >> 16));
  float xhv = bf2f(xhw);

  float rg = sigm_pre(xrv + ((r0[0] + r1[0]) + (r2[0] + r3[0])));
  float rh = rg * h_own;
  if (own)
    rhx[u] = (__bf16)rh;                 // b16, 2 lanes/dword: conflict-free
  zrw = xzr[ub + tp * H_DIM];            // refill AFTER write: covers latency
  BARRIER();                             // rh visible

  // ---- phase B: z (register h frags; hides under rh read) + h~ + update ----
  bf16x8 b0 = *reinterpret_cast<const bf16x8*>(&rhx[      g8 * 8]);
  bf16x8 b1 = *reinterpret_cast<const bf16x8*>(&rhx[32  + g8 * 8]);
  bf16x8 b2 = *reinterpret_cast<const bf16x8*>(&rhx[64  + g8 * 8]);
  bf16x8 b3 = *reinterpret_cast<const bf16x8*>(&rhx[96  + g8 * 8]);
  f32x4 z0 = MFMA(a0, ufz[0], zero);
  f32x4 z1 = MFMA(a1, ufz[1], zero);
  f32x4 z2 = MFMA(a2, ufz[2], zero);
  f32x4 z3 = MFMA(a3, ufz[3], zero);
  f32x4 h0 = MFMA(b0, ufh[0], zero);
  f32x4 h1 = MFMA(b1, ufh[1], zero);
  f32x4 h2 = MFMA(b2, ufh[2], zero);
  f32x4 h3 = MFMA(b3, ufh[3], zero);

  float zg = sigm_pre(xzv + ((z0[0] + z1[0]) + (z2[0] + z3[0])));
  float hc = tanh_pre(xhv + ((h0[0] + h1[0]) + (h2[0] + h3[0])));
  float hn = fmaf(zg, hc - h_own, h_own);               // (1-z)h + z*hc
  h_own = hn;
  if (own){
    hx[u] = (__bf16)hn;
    out[ub + t * H_DIM] = hn;                           // fire-and-forget
  }
  xhw = xh[ub + tp * H_DIM];             // refill AFTER write: covers latency
  BARRIER();                             // h' visible
}

__global__ __launch_bounds__(512, 1) void gru_rec8q(
    const float* __restrict__ Uz, const float* __restrict__ Ur, const float* __restrict__ Uh,
    const int* __restrict__ lengths,
    const unsigned int* xzr,            // aliases `out` (packed bf16 xz|xr)
    const unsigned short* __restrict__ xh,
    float* out)
{
  __shared__ __align__(16) __bf16 hx[H_DIM];
  __shared__ __align__(16) __bf16 rhx[H_DIM];

  const int tid = threadIdx.x;
  const int w = tid >> 6, l = tid & 63;
  const int g8 = l >> 4;                // k-slice within each 32-k block
  const int u  = w * 16 + (l & 15);     // owned unit (C col)
  const int b  = blockIdx.x;
  const int len = lengths[b];

  // U B-fragments, prescaled: 3 gates x 4 k-steps x 4 VGPR = 48 VGPRs
  bf16x8 ufz[4], ufr[4], ufh[4];
  #pragma unroll
  for (int kk = 0; kk < 4; ++kk){
    const int ko = kk * 32 + g8 * 8;
    ufz[kk] = ld_u_frag_s(Uz + u * H_DIM + ko, KNEG);
    ufr[kk] = ld_u_frag_s(Ur + u * H_DIM + ko, KNEG);
    ufh[kk] = ld_u_frag_s(Uh + u * H_DIM + ko, KPOS);
  }

  if (tid < 64) reinterpret_cast<unsigned int*>(hx)[tid] = 0u;  // h0 = 0
  float h_own = 0.f;
  __syncthreads();

  const int ub = b * (T_LEN * H_DIM) + u;   // element offset of (b, t=0, u)

  // 6-deep prefetch, named register sets (slots t .. t+5)
  unsigned int  zrA = xzr[ub];
  unsigned int  zrB = xzr[ub + 1 * H_DIM];
  unsigned int  zrC = xzr[ub + 2 * H_DIM];
  unsigned int  zrD = xzr[ub + 3 * H_DIM];
  unsigned int  zrE = xzr[ub + 4 * H_DIM];
  unsigned int  zrF = xzr[ub + 5 * H_DIM];
  unsigned short xhA = xh[ub];
  unsigned short xhB = xh[ub + 1 * H_DIM];
  unsigned short xhC = xh[ub + 2 * H_DIM];
  unsigned short xhD = xh[ub + 3 * H_DIM];
  unsigned short xhE = xh[ub + 4 * H_DIM];
  unsigned short xhF = xh[ub + 5 * H_DIM];

  int t = 0;
  for (; t + 5 < len; t += 6){
    gru_step8(t,   ub, g8, l, w, ufz, ufr, ufh, hx, rhx, xzr, xh, out, zrA, xhA, h_own);
    gru_step8(t+1, ub, g8, l, w, ufz, ufr, ufh, hx, rhx, xzr, xh, out, zrB, xhB, h_own);
    gru_step8(t+2, ub, g8, l, w, ufz, ufr, ufh, hx, rhx, xzr, xh, out, zrC, xhC, h_own);
    gru_step8(t+3, ub, g8, l, w, ufz, ufr, ufh, hx, rhx, xzr, xh, out, zrD, xhD, h_own);
    gru_step8(t+4, ub, g8, l, w, ufz, ufr, ufh, hx, rhx, xzr, xh, out, zrE, xhE, h_own);
    gru_step8(t+5, ub, g8, l, w, ufz, ufr, ufh, hx, rhx, xzr, xh, out, zrF, xhF, h_own);
  }
  if (t < len)
    gru_step8(t,   ub, g8, l, w, ufz, ufr, ufh, hx, rhx, xzr, xh, out, zrA, xhA, h_own);
  if (t + 1 < len)
    gru_step8(t+1, ub, g8, l, w, ufz, ufr, ufh, hx, rhx, xzr, xh, out, zrB, xhB, h_own);
  if (t + 2 < len)
    gru_step8(t+2, ub, g8, l, w, ufz, ufr, ufh, hx, rhx, xzr, xh, out, zrC, xhC, h_own);
  if (t + 3 < len)
    gru_step8(t+3, ub, g8, l, w, ufz, ufr, ufh, hx, rhx, xzr, xh, out, zrD, xhD, h_own);
  if (t + 4 < len)
    gru_step8(t+4, ub, g8, l, w, ufz, ufr, ufh, hx, rhx, xzr, xh, out, zrE, xhE, h_own);

  // masked region: exact zeros for t >= len (disjoint from h-stores)
  const long base = (long)b * (T_LEN * H_DIM);
  for (long i = (long)len * H_DIM + tid * 4; i < (long)T_LEN * H_DIM; i += 512 * 4){
    *reinterpret_cast<float4*>(out + base + i) = make_float4(0.f, 0.f, 0.f, 0.f);
  }
}

extern "C" void kernel_launch(void* const* d_in, const int* in_sizes, int n_in,
                              void* d_out, int out_size, void* d_ws, size_t ws_size,
                              hipStream_t stream){
  const float* x       = (const float*)d_in[0];
  const int*   lengths = (const int*)  d_in[1];
  const float* Wz = (const float*)d_in[2];
  const float* Uz = (const float*)d_in[3];
  const float* bz = (const float*)d_in[4];
  const float* Wr = (const float*)d_in[5];
  const float* Ur = (const float*)d_in[6];
  const float* br = (const float*)d_in[7];
  const float* Wh = (const float*)d_in[8];
  const float* Uh = (const float*)d_in[9];
  const float* bh = (const float*)d_in[10];

  unsigned int*   zr    = (unsigned int*)d_out;   // packed bf16 xz|xr, then h
  unsigned short* xhbuf = (unsigned short*)d_ws;  // bf16 xh

  gru_proj<<<dim3(2048), dim3(512), 0, stream>>>(x, Wz, Wr, Wh, bz, br, bh, zr, xhbuf);
  gru_rec8q<<<dim3(128), dim3(512), 0, stream>>>(Uz, Ur, Uh, lengths, zr, xhbuf, (float*)d_out);
}